// Round 3
// baseline (1982.034 us; speedup 1.0000x reference)
//
#include <hip/hip_runtime.h>
#include <hip/hip_bf16.h>
#include <math.h>

typedef float f32x4 __attribute__((ext_vector_type(4)));
typedef __bf16 bf16x8 __attribute__((ext_vector_type(8)));
typedef unsigned short u16x4 __attribute__((ext_vector_type(4)));

// LDS layout. All row strides are multiples of 16 (b128 alignment) chosen so
// (stride/4)%32 spreads 16 consecutive rows across banks at <=2-way (free).
#define SA_BASE   0        // [64 tok][192 ch] bf16, stride 400B -> 25600. h / h2 (per-wave rows)
#define SA_STR    400      // 400/4=100 -> bank start 4*row: 2-way over 16 rows
#define SK_BASE   25600    // [64 tok][32 kch] bf16, stride 80 -> 5120 (shared, cur head)
#define SK_STR    80       // 80/4=20 -> bank start 20*row: 2-way
#define SVT_BASE  30720    // [32 d][64 tok] bf16, stride 144 -> 4608 (shared, cur head, V^T)
#define SVT_STR   144      // 144/4=36 -> bank start 4*row: 2-way
#define PRIV_BASE 35328    // per-wave 3584: {SQ|SO alias [16][80]=1280, SP [16][144]=2304}
#define PRIV_SZ   3584
#define SP_OFF    1280
#define SG_BASE   25600    // MLP gelu, per-wave [16][400]=6400 -> 25600..51200 (overlays attn bufs)
#define SG_STR    400
#define SMEM_BYTES 51200   // 3 blocks/CU (160K)

__device__ __forceinline__ unsigned short f2b(float x){ return __builtin_bit_cast(unsigned short, (__bf16)x); }

// Transpose + cast weights to bf16 [N][K] so MFMA fragments are 8 contiguous k-elems.
__global__ void prep_weights(const float* __restrict__ wqkv, const float* __restrict__ wproj,
                             const float* __restrict__ wmlp1, const float* __restrict__ wmlp2,
                             unsigned short* __restrict__ ws){
  int idx = blockIdx.x*256 + threadIdx.x;
  if (idx < 110592){ int n=idx/192, k=idx%192; ws[idx] = f2b(wqkv[k*576+n]); }
  else if (idx < 147456){ int i=idx-110592; int n=i/192, k=i%192; ws[idx] = f2b(wproj[k*192+n]); }
  else if (idx < 294912){ int i=idx-147456; int n=i/192, k=i%192; ws[idx] = f2b(wmlp1[k*768+n]); }
  else if (idx < 442368){ int i=idx-294912; int n=i/768, k=i%768; ws[idx] = f2b(wmlp2[k*192+n]); }
}

__global__ void __launch_bounds__(256, 3) winblock(
    const float* __restrict__ x,
    const float* __restrict__ bqkv, const float* __restrict__ bproj,
    const float* __restrict__ ln1g, const float* __restrict__ ln1b,
    const float* __restrict__ ln2g, const float* __restrict__ ln2b,
    const float* __restrict__ bmlp1, const float* __restrict__ bmlp2,
    const unsigned short* __restrict__ wqkvT, const unsigned short* __restrict__ wprojT,
    const unsigned short* __restrict__ wmlp1T, const unsigned short* __restrict__ wmlp2T,
    float* __restrict__ out)
{
  __shared__ __align__(16) char sm[SMEM_BYTES];
  const int tid=threadIdx.x, w=tid>>6, l=tid&63, l16=l&15, lg=l>>4;
  const int wid=blockIdx.x;
  const int bb=wid>>10, wh=(wid>>5)&31, wwi=wid&31;
  const size_t imgoff=(size_t)bb*192*65536 + (size_t)(wh*8)*256 + (size_t)(wwi*8);
  const int tok = w*16 + l16;                        // this thread's token
  const int tokpos = (tok>>3)*256 + (tok&7);         // offset within image plane
  char* const priv = sm + PRIV_BASE + w*PRIV_SZ;     // SQ/SO alias at +0, SP at +SP_OFF
  char* const sgw  = sm + SG_BASE + w*6400;

  // ---- Phase A: residual t: 48 f32, ch = 16*i4 + 4*lg + r  (i = i4*4+r) ----
  float t[48];
  #pragma unroll
  for(int i4=0;i4<12;++i4){
    #pragma unroll
    for(int r=0;r<4;++r)
      t[i4*4+r]=x[imgoff+(size_t)(16*i4+4*lg+r)*65536+(size_t)tokpos];
  }

  // ---- Phase B: LN1 (cross-lane over lg group only) -> sA rows of own wave ----
  {
    float s=0.f,s2=0.f;
    #pragma unroll
    for(int i=0;i<48;++i){ s+=t[i]; s2+=t[i]*t[i]; }
    s+=__shfl_xor(s,16); s+=__shfl_xor(s,32);
    s2+=__shfl_xor(s2,16); s2+=__shfl_xor(s2,32);
    float mean=s*(1.f/192.f), var=s2*(1.f/192.f)-mean*mean, rstd=rsqrtf(var+1e-5f);
    #pragma unroll
    for(int i4=0;i4<12;++i4){
      const f32x4 g4=*(const f32x4*)(ln1g+16*i4+4*lg);
      const f32x4 b4=*(const f32x4*)(ln1b+16*i4+4*lg);
      u16x4 pk;
      #pragma unroll
      for(int r=0;r<4;++r) pk[r]=f2b((t[i4*4+r]-mean)*rstd*g4[r]+b4[r]);
      *(u16x4*)(sm+SA_BASE+tok*SA_STR+(16*i4+4*lg)*2)=pk;   // same-wave rows only
    }
  }

  // persistent accumulator (proj now, MLP2 later): D rows = out-ch 16*mt+4lg+r, col = own tok
  f32x4 acc12[12];
  #pragma unroll
  for(int mt=0;mt<12;++mt) acc12[mt]=(f32x4){0.f,0.f,0.f,0.f};

  // ================= attention heads =================
  #pragma unroll 1
  for(int h=0;h<6;++h){
    if(h) __syncthreads();    // WAR: SK/SVT of previous head still being read
    // ---- C1: QKV (A=W global, B=h from own sA rows). D: (ch, own tok). ----
    {
      f32x4 qa[2],ka[2],va[2];
      #pragma unroll
      for(int mt=0;mt<2;++mt){ qa[mt]=(f32x4){0,0,0,0}; ka[mt]=(f32x4){0,0,0,0}; va[mt]=(f32x4){0,0,0,0}; }
      #pragma unroll
      for(int ks=0;ks<6;++ks){
        const bf16x8 bh=*(const bf16x8*)(sm+SA_BASE+tok*SA_STR+ks*64+lg*16);
        #pragma unroll
        for(int mt=0;mt<2;++mt){
          const bf16x8 awq=*(const bf16x8*)(wqkvT+(      h*32+mt*16+l16)*192+ks*32+lg*8);
          qa[mt]=__builtin_amdgcn_mfma_f32_16x16x32_bf16(awq,bh,qa[mt],0,0,0);
          const bf16x8 awk=*(const bf16x8*)(wqkvT+(192 + h*32+mt*16+l16)*192+ks*32+lg*8);
          ka[mt]=__builtin_amdgcn_mfma_f32_16x16x32_bf16(awk,bh,ka[mt],0,0,0);
          const bf16x8 awv=*(const bf16x8*)(wqkvT+(384 + h*32+mt*16+l16)*192+ks*32+lg*8);
          va[mt]=__builtin_amdgcn_mfma_f32_16x16x32_bf16(awv,bh,va[mt],0,0,0);
        }
      }
      #pragma unroll
      for(int mt=0;mt<2;++mt){
        const f32x4 bq4=*(const f32x4*)(bqkv+      h*32+mt*16+4*lg);
        const f32x4 bk4=*(const f32x4*)(bqkv+192 + h*32+mt*16+4*lg);
        u16x4 pq,pk;
        #pragma unroll
        for(int r=0;r<4;++r){ pq[r]=f2b(qa[mt][r]+bq4[r]); pk[r]=f2b(ka[mt][r]+bk4[r]); }
        // Q -> private [own tok row][qch], K -> shared [tok][kch]: 4 consecutive ch -> u16x4
        *(u16x4*)(priv+l16*SK_STR+(mt*16+4*lg)*2)=pq;
        *(u16x4*)(sm+SK_BASE+tok*SK_STR+(mt*16+4*lg)*2)=pk;
        const float bv=bqkv[384+h*32+mt*16+4*lg];   // scalar per r below
        #pragma unroll
        for(int r=0;r<4;++r)
          *(unsigned short*)(sm+SVT_BASE+(mt*16+4*lg+r)*SVT_STR+tok*2)
            = f2b(va[mt][r]+bqkv[384+h*32+mt*16+4*lg+r]);
        (void)bv;
      }
    }
    __syncthreads();          // RAW: K,V visible to all waves
    // ---- C2: S^T = K·Q^T (A=K shared, B=Q private). D: (ktok, own q). softmax in-reg ----
    f32x4 ap_hold[2];
    {
      const bf16x8 bq=*(const bf16x8*)(priv+l16*SK_STR+lg*16);
      f32x4 sv[4];
      #pragma unroll
      for(int kt=0;kt<4;++kt){
        const bf16x8 ak=*(const bf16x8*)(sm+SK_BASE+(kt*16+l16)*SK_STR+lg*16);
        sv[kt]=__builtin_amdgcn_mfma_f32_16x16x32_bf16(ak,bq,(f32x4){0,0,0,0},0,0,0);
      }
      const float scale=0.17677669529663687f; // 1/sqrt(32)
      float mx=-3.0e38f;
      #pragma unroll
      for(int kt=0;kt<4;++kt){
        #pragma unroll
        for(int r=0;r<4;++r) mx=fmaxf(mx,sv[kt][r]);
      }
      mx=fmaxf(mx,__shfl_xor(mx,16)); mx=fmaxf(mx,__shfl_xor(mx,32));
      float sum=0.f;
      #pragma unroll
      for(int kt=0;kt<4;++kt){
        #pragma unroll
        for(int r=0;r<4;++r){ float e=__expf((sv[kt][r]-mx)*scale); sv[kt][r]=e; sum+=e; }
      }
      sum+=__shfl_xor(sum,16); sum+=__shfl_xor(sum,32);
      const float rs=1.f/sum;
      #pragma unroll
      for(int kt=0;kt<4;++kt){
        u16x4 pp;
        #pragma unroll
        for(int r=0;r<4;++r) pp[r]=f2b(sv[kt][r]*rs);
        *(u16x4*)(priv+SP_OFF+l16*SVT_STR+(kt*16+4*lg)*2)=pp;  // own q row, 4 consecutive k
      }
      // same-wave round trip (compiler inserts lgkmcnt)
      #pragma unroll
      for(int ks2=0;ks2<2;++ks2)
        ap_hold[ks2]=__builtin_bit_cast(f32x4, *(const bf16x8*)(priv+SP_OFF+l16*SVT_STR+ks2*64+lg*16));
    }
    // ---- C3: O = P·V (A=P own rows, B=V^T shared). D: (own q-tile rows, d) ----
    {
      f32x4 ov[2]={(f32x4){0,0,0,0},(f32x4){0,0,0,0}};
      #pragma unroll
      for(int dt=0;dt<2;++dt){
        #pragma unroll
        for(int ks2=0;ks2<2;++ks2){
          const bf16x8 bv=*(const bf16x8*)(sm+SVT_BASE+(dt*16+l16)*SVT_STR+ks2*64+lg*16);
          ov[dt]=__builtin_amdgcn_mfma_f32_16x16x32_bf16(
                   __builtin_bit_cast(bf16x8, ap_hold[ks2]),bv,ov[dt],0,0,0);
        }
      }
      // O -> private [q-in-tile row][d] (rows 4lg+r, cols 16 contiguous d per instr)
      #pragma unroll
      for(int dt=0;dt<2;++dt){
        #pragma unroll
        for(int r=0;r<4;++r)
          *(unsigned short*)(priv+(4*lg+r)*SK_STR+(dt*16+l16)*2)=f2b(ov[dt][r]);
      }
    }
    // ---- C4: proj accumulate (A=Wproj global, B=O own rows) ----
    {
      const bf16x8 bo=*(const bf16x8*)(priv+l16*SK_STR+lg*16);
      #pragma unroll
      for(int mt=0;mt<12;++mt){
        const bf16x8 aw=*(const bf16x8*)(wprojT+(mt*16+l16)*192+h*32+lg*8);
        acc12[mt]=__builtin_amdgcn_mfma_f32_16x16x32_bf16(aw,bo,acc12[mt],0,0,0);
      }
    }
  }
  __syncthreads();   // attn shared buffers done before SG overlay writes

  // ---- Phase D: t += proj + bias (pure registers; distributions match) ----
  #pragma unroll
  for(int mt=0;mt<12;++mt){
    const f32x4 bp=*(const f32x4*)(bproj+16*mt+4*lg);
    #pragma unroll
    for(int r=0;r<4;++r) t[mt*4+r]+=acc12[mt][r]+bp[r];
    acc12[mt]=(f32x4){0.f,0.f,0.f,0.f};    // reuse for MLP2
  }

  // ---- Phase E: LN2 -> h2 in own sA rows (no barrier: rows are wave-private) ----
  {
    float s=0.f,s2=0.f;
    #pragma unroll
    for(int i=0;i<48;++i){ s+=t[i]; s2+=t[i]*t[i]; }
    s+=__shfl_xor(s,16); s+=__shfl_xor(s,32);
    s2+=__shfl_xor(s2,16); s2+=__shfl_xor(s2,32);
    float mean=s*(1.f/192.f), var=s2*(1.f/192.f)-mean*mean, rstd=rsqrtf(var+1e-5f);
    #pragma unroll
    for(int i4=0;i4<12;++i4){
      const f32x4 g4=*(const f32x4*)(ln2g+16*i4+4*lg);
      const f32x4 b4=*(const f32x4*)(ln2b+16*i4+4*lg);
      u16x4 pk;
      #pragma unroll
      for(int r=0;r<4;++r) pk[r]=f2b((t[i4*4+r]-mean)*rstd*g4[r]+b4[r]);
      *(u16x4*)(sm+SA_BASE+tok*SA_STR+(16*i4+4*lg)*2)=pk;
    }
  }

  // ---- Phase F: MLP, 4 chunks of 192 mlp-ch; zero barriers (all same-wave LDS) ----
  #pragma unroll 1
  for(int qc=0;qc<4;++qc){
    #pragma unroll 1
    for(int half=0;half<2;++half){
      f32x4 g[6];
      #pragma unroll
      for(int m=0;m<6;++m) g[m]=(f32x4){0,0,0,0};
      #pragma unroll
      for(int ks=0;ks<6;++ks){
        const bf16x8 bh2=*(const bf16x8*)(sm+SA_BASE+tok*SA_STR+ks*64+lg*16);
        #pragma unroll
        for(int m=0;m<6;++m){
          const int mt=half*6+m;
          const bf16x8 aw=*(const bf16x8*)(wmlp1T+(qc*192+mt*16+l16)*192+ks*32+lg*8);
          g[m]=__builtin_amdgcn_mfma_f32_16x16x32_bf16(aw,bh2,g[m],0,0,0);
        }
      }
      #pragma unroll
      for(int m=0;m<6;++m){
        const int mt=half*6+m;
        const f32x4 b1=*(const f32x4*)(bmlp1+qc*192+mt*16+4*lg);
        u16x4 pg;
        #pragma unroll
        for(int r=0;r<4;++r){
          const float xv=g[m][r]+b1[r];
          pg[r]=f2b(0.5f*xv*(1.f+erff(xv*0.70710678118654752f)));
        }
        *(u16x4*)(sgw+l16*SG_STR+(mt*16+4*lg)*2)=pg;   // own rows
      }
    }
    #pragma unroll
    for(int ks2=0;ks2<6;++ks2){
      const bf16x8 bg=*(const bf16x8*)(sgw+l16*SG_STR+ks2*64+lg*16);
      #pragma unroll
      for(int mt=0;mt<12;++mt){
        const bf16x8 aw2=*(const bf16x8*)(wmlp2T+(mt*16+l16)*768+qc*192+ks2*32+lg*8);
        acc12[mt]=__builtin_amdgcn_mfma_f32_16x16x32_bf16(aw2,bg,acc12[mt],0,0,0);
      }
    }
  }

  // ---- Phase G: out = t + mlp + bias (registers -> global) ----
  #pragma unroll
  for(int mt=0;mt<12;++mt){
    const f32x4 b2=*(const f32x4*)(bmlp2+16*mt+4*lg);
    #pragma unroll
    for(int r=0;r<4;++r)
      out[imgoff+(size_t)(16*mt+4*lg+r)*65536+(size_t)tokpos]=t[mt*4+r]+acc12[mt][r]+b2[r];
  }
}

extern "C" void kernel_launch(void* const* d_in, const int* in_sizes, int n_in,
                              void* d_out, int out_size, void* d_ws, size_t ws_size,
                              hipStream_t stream) {
  const float* x      = (const float*)d_in[0];
  const float* w_qkv  = (const float*)d_in[1];
  const float* b_qkv  = (const float*)d_in[2];
  const float* w_proj = (const float*)d_in[3];
  const float* b_proj = (const float*)d_in[4];
  const float* ln1g   = (const float*)d_in[5];
  const float* ln1b   = (const float*)d_in[6];
  const float* ln2g   = (const float*)d_in[7];
  const float* ln2b   = (const float*)d_in[8];
  const float* w_mlp1 = (const float*)d_in[9];
  const float* b_mlp1 = (const float*)d_in[10];
  const float* w_mlp2 = (const float*)d_in[11];
  const float* b_mlp2 = (const float*)d_in[12];
  unsigned short* wsu = (unsigned short*)d_ws;

  prep_weights<<<dim3(1728), dim3(256), 0, stream>>>(w_qkv, w_proj, w_mlp1, w_mlp2, wsu);
  winblock<<<dim3(4096), dim3(256), 0, stream>>>(
      x, b_qkv, b_proj, ln1g, ln1b, ln2g, ln2b, b_mlp1, b_mlp2,
      wsu, wsu+110592, wsu+147456, wsu+294912, (float*)d_out);
}

// Round 4
// 1235.629 us; speedup vs baseline: 1.6041x; 1.6041x over previous
//
#include <hip/hip_runtime.h>
#include <hip/hip_bf16.h>
#include <math.h>

typedef float f32x4 __attribute__((ext_vector_type(4)));
typedef float f32x2 __attribute__((ext_vector_type(2)));
typedef __bf16 bf16x8 __attribute__((ext_vector_type(8)));
typedef unsigned short u16x4 __attribute__((ext_vector_type(4)));

// ---------------- LDS map (48 KB -> 3 blocks/CU) ----------------
// SA : h/h2  [64 tok][192 ch] bf16, stride 384, XOR ((tok&7)<<4)
// R2 : attn {Q,K [64][32] str64 XOR((r&3)<<4); VT [32][64] str128 XOR((r&7)<<4);
//            P [64][64] str128 XOR((r&7)<<4); O [64][32] str64}  = 24576
//      | MLP G [64][192] str384 XOR((r&7)<<4)  | LN red float2[4][64]
#define SA_B  0
#define R2_B  24576
#define RQ_B  (R2_B)
#define RK_B  (R2_B+4096)
#define RVT_B (R2_B+8192)
#define RP_B  (R2_B+12288)
#define RO_B  (R2_B+20480)
#define RG_B  (R2_B)
#define SMEM  49152

__device__ __forceinline__ int sa_off(int row,int byte){ return SA_B + row*384 + (byte ^ ((row&7)<<4)); }
__device__ __forceinline__ int g_off (int row,int byte){ return RG_B + row*384 + (byte ^ ((row&7)<<4)); }
__device__ __forceinline__ int q_off (int row,int byte){ return RQ_B + row*64  + (byte ^ ((row&3)<<4)); }
__device__ __forceinline__ int k_off (int row,int byte){ return RK_B + row*64  + (byte ^ ((row&3)<<4)); }
__device__ __forceinline__ int o_off (int row,int byte){ return RO_B + row*64  + (byte ^ ((row&3)<<4)); }
__device__ __forceinline__ int vt_off(int row,int byte){ return RVT_B+ row*128 + (byte ^ ((row&7)<<4)); }
__device__ __forceinline__ int p_off (int row,int byte){ return RP_B + row*128 + (byte ^ ((row&7)<<4)); }
__device__ __forceinline__ unsigned short f2b(float x){ return __builtin_bit_cast(unsigned short, (__bf16)x); }

// Transpose + cast weights to bf16 [N][K]
__global__ void prep_weights(const float* __restrict__ wqkv, const float* __restrict__ wproj,
                             const float* __restrict__ wmlp1, const float* __restrict__ wmlp2,
                             unsigned short* __restrict__ ws){
  int idx = blockIdx.x*256 + threadIdx.x;
  if (idx < 110592){ int n=idx/192, k=idx%192; ws[idx] = f2b(wqkv[k*576+n]); }
  else if (idx < 147456){ int i=idx-110592; int n=i/192, k=i%192; ws[idx] = f2b(wproj[k*192+n]); }
  else if (idx < 294912){ int i=idx-147456; int n=i/192, k=i%192; ws[idx] = f2b(wmlp1[k*768+n]); }
  else if (idx < 442368){ int i=idx-294912; int n=i/768, k=i%768; ws[idx] = f2b(wmlp2[k*192+n]); }
}

// K1: x[B,C,H,W] -> xw[win][tok][192] (all coalesced)
__global__ void relayout_in(const float* __restrict__ x, float* __restrict__ xw){
  const int w = threadIdx.x, bh = blockIdx.x, b = bh>>8, h = bh&255;
  const int win = b*1024 + (h>>3)*32 + (w>>3);
  const int tok = (h&7)*8 + (w&7);
  const size_t src = (size_t)b*192*65536 + (size_t)h*256 + w;
  float* dst = xw + (size_t)win*12288 + tok*192;
  #pragma unroll 1
  for(int c0=0;c0<192;c0+=32){
    float buf[32];
    #pragma unroll
    for(int j=0;j<32;++j) buf[j] = x[src + (size_t)(c0+j)*65536];
    #pragma unroll
    for(int j4=0;j4<8;++j4)
      *(f32x4*)(dst + c0 + j4*4) = (f32x4){buf[j4*4],buf[j4*4+1],buf[j4*4+2],buf[j4*4+3]};
  }
}

// K3: rw[win][tok][192] -> out[B,C,H,W] (all coalesced)
__global__ void relayout_out(const float* __restrict__ rw, float* __restrict__ out){
  const int w = threadIdx.x, bh = blockIdx.x, b = bh>>8, h = bh&255;
  const int win = b*1024 + (h>>3)*32 + (w>>3);
  const int tok = (h&7)*8 + (w&7);
  const float* src = rw + (size_t)win*12288 + tok*192;
  const size_t dst = (size_t)b*192*65536 + (size_t)h*256 + w;
  #pragma unroll 1
  for(int c0=0;c0<192;c0+=32){
    f32x4 buf[8];
    #pragma unroll
    for(int j4=0;j4<8;++j4) buf[j4] = *(const f32x4*)(src + c0 + j4*4);
    #pragma unroll
    for(int j=0;j<32;++j) out[dst + (size_t)(c0+j)*65536] = buf[j>>2][j&3];
  }
}

// K2: fused block. Thread (w,lg,l16) owns toks {16tt+l16} x chs {48w+16mt+4lg+r}.
template<int DIRECT>
__global__ void __launch_bounds__(256, 3) winblock(
    const float* xin, float* outp,
    const float* __restrict__ bqkv, const float* __restrict__ bproj,
    const float* __restrict__ ln1g, const float* __restrict__ ln1b,
    const float* __restrict__ ln2g, const float* __restrict__ ln2b,
    const float* __restrict__ bmlp1, const float* __restrict__ bmlp2,
    const unsigned short* __restrict__ wqkvT, const unsigned short* __restrict__ wprojT,
    const unsigned short* __restrict__ wmlp1T, const unsigned short* __restrict__ wmlp2T)
{
  __shared__ __align__(16) char sm[SMEM];
  const int tid=threadIdx.x, w=tid>>6, lg=(tid>>4)&3, l16=tid&15;
  const int wid=blockIdx.x;
  const int bb=wid>>10, wh=(wid>>5)&31, wwi=wid&31;
  const size_t imgoff=(size_t)bb*192*65536 + (size_t)(wh*8)*256 + (size_t)(wwi*8);
  f32x2* red = (f32x2*)(sm + R2_B);

  // ---- Phase A: residual t[mt][tt][r] ----
  f32x4 t[3][4];
  if(DIRECT){
    #pragma unroll
    for(int mt=0;mt<3;++mt)
      #pragma unroll
      for(int tt=0;tt<4;++tt){
        const int T=16*tt+l16, tp=(T>>3)*256+(T&7);
        #pragma unroll
        for(int r=0;r<4;++r)
          t[mt][tt][r]=xin[imgoff+(size_t)(48*w+16*mt+4*lg+r)*65536+tp];
      }
  } else {
    const float* base = xin + (size_t)wid*12288;
    #pragma unroll
    for(int mt=0;mt<3;++mt)
      #pragma unroll
      for(int tt=0;tt<4;++tt)
        t[mt][tt]=*(const f32x4*)(base + (16*tt+l16)*192 + 48*w+16*mt+4*lg);
  }

  // ---- LayerNorm helper (writes bf16 normalized into SA) ----
  auto layernorm = [&](const float* gg, const float* bbv){
    float s[4], s2[4];
    #pragma unroll
    for(int tt=0;tt<4;++tt){
      float a=0.f,b2=0.f;
      #pragma unroll
      for(int mt=0;mt<3;++mt){
        #pragma unroll
        for(int r=0;r<4;++r){ a+=t[mt][tt][r]; b2+=t[mt][tt][r]*t[mt][tt][r]; }
      }
      a+=__shfl_xor(a,16); a+=__shfl_xor(a,32);
      b2+=__shfl_xor(b2,16); b2+=__shfl_xor(b2,32);
      s[tt]=a; s2[tt]=b2;
    }
    if(lg==0) red[w*64 +  0+l16]=(f32x2){s[0],s2[0]};
    if(lg==1) red[w*64 + 16+l16]=(f32x2){s[1],s2[1]};
    if(lg==2) red[w*64 + 32+l16]=(f32x2){s[2],s2[2]};
    if(lg==3) red[w*64 + 48+l16]=(f32x2){s[3],s2[3]};
    __syncthreads();
    float mean[4], rstd[4];
    #pragma unroll
    for(int tt=0;tt<4;++tt){
      float S=0.f,S2=0.f;
      #pragma unroll
      for(int w2=0;w2<4;++w2){ f32x2 v=red[w2*64+16*tt+l16]; S+=v.x; S2+=v.y; }
      mean[tt]=S*(1.f/192.f);
      rstd[tt]=rsqrtf(S2*(1.f/192.f)-mean[tt]*mean[tt]+1e-5f);
    }
    #pragma unroll
    for(int mt=0;mt<3;++mt){
      const f32x4 g4=*(const f32x4*)(gg+48*w+16*mt+4*lg);
      const f32x4 b4=*(const f32x4*)(bbv+48*w+16*mt+4*lg);
      #pragma unroll
      for(int tt=0;tt<4;++tt){
        u16x4 pk;
        #pragma unroll
        for(int r=0;r<4;++r) pk[r]=f2b((t[mt][tt][r]-mean[tt])*rstd[tt]*g4[r]+b4[r]);
        *(u16x4*)(sm+sa_off(16*tt+l16,(48*w+16*mt+4*lg)*2))=pk;
      }
    }
  };

  layernorm(ln1g, ln1b);
  __syncthreads();   // h visible

  f32x4 acc[3][4];
  #pragma unroll
  for(int mt=0;mt<3;++mt){
    #pragma unroll
    for(int tt=0;tt<4;++tt) acc[mt][tt]=(f32x4){0.f,0.f,0.f,0.f};
  }

  // ---- QKV producer for head hh: wave (w): ct=w>>1, tok-tiles {2*(w&1), +1} ----
  const int ct=w>>1, tbase=2*(w&1);
  const float qscale=0.17677669529663687f;   // 1/sqrt(32), folded into Q
  auto c1=[&](int hh){
    f32x4 qa[2],ka[2],va[2];
    #pragma unroll
    for(int i=0;i<2;++i){ qa[i]=(f32x4){0,0,0,0}; ka[i]=(f32x4){0,0,0,0}; va[i]=(f32x4){0,0,0,0}; }
    #pragma unroll
    for(int ks=0;ks<6;++ks){
      bf16x8 hfrag[2];
      #pragma unroll
      for(int i=0;i<2;++i) hfrag[i]=*(const bf16x8*)(sm+sa_off(16*(tbase+i)+l16, ks*64+lg*16));
      const bf16x8 awq=*(const bf16x8*)(wqkvT+(      hh*32+ct*16+l16)*192+ks*32+lg*8);
      const bf16x8 awk=*(const bf16x8*)(wqkvT+(192 + hh*32+ct*16+l16)*192+ks*32+lg*8);
      const bf16x8 bwv=*(const bf16x8*)(wqkvT+(384 + hh*32+ct*16+l16)*192+ks*32+lg*8);
      #pragma unroll
      for(int i=0;i<2;++i){
        qa[i]=__builtin_amdgcn_mfma_f32_16x16x32_bf16(awq,hfrag[i],qa[i],0,0,0);  // D[qch][tok]
        ka[i]=__builtin_amdgcn_mfma_f32_16x16x32_bf16(awk,hfrag[i],ka[i],0,0,0);
        va[i]=__builtin_amdgcn_mfma_f32_16x16x32_bf16(hfrag[i],bwv,va[i],0,0,0);  // D[tok][vch]
      }
    }
    const f32x4 bq4=*(const f32x4*)(bqkv+      hh*32+ct*16+4*lg);
    const f32x4 bk4=*(const f32x4*)(bqkv+192 + hh*32+ct*16+4*lg);
    const float bv =bqkv[384 + hh*32+ct*16+l16];
    #pragma unroll
    for(int i=0;i<2;++i){
      const int tok=16*(tbase+i)+l16;
      u16x4 pq,pk,pv;
      #pragma unroll
      for(int r=0;r<4;++r){
        pq[r]=f2b((qa[i][r]+bq4[r])*qscale);
        pk[r]=f2b(ka[i][r]+bk4[r]);
        pv[r]=f2b(va[i][r]+bv);
      }
      *(u16x4*)(sm+q_off(tok,(ct*16+4*lg)*2))=pq;               // Q[tok][qch]
      *(u16x4*)(sm+k_off(tok,(ct*16+4*lg)*2))=pk;               // K[tok][qch]
      *(u16x4*)(sm+vt_off(ct*16+l16,(16*(tbase+i)+4*lg)*2))=pv; // VT[vch][tok]
    }
  };

  c1(0);
  __syncthreads();

  #pragma unroll 1
  for(int h=0;h<6;++h){
    // ---- S = K.Q^T (A=K rows=ktok, B=Q cols=own q) ; softmax in-register ----
    {
      const int q=16*w+l16;
      const bf16x8 bqf=*(const bf16x8*)(sm+q_off(q,lg*16));
      f32x4 sv[4];
      #pragma unroll
      for(int kt=0;kt<4;++kt){
        const bf16x8 akf=*(const bf16x8*)(sm+k_off(16*kt+l16,lg*16));
        sv[kt]=__builtin_amdgcn_mfma_f32_16x16x32_bf16(akf,bqf,(f32x4){0,0,0,0},0,0,0);
      }
      float mx=-3.0e38f;
      #pragma unroll
      for(int kt=0;kt<4;++kt){
        #pragma unroll
        for(int r=0;r<4;++r) mx=fmaxf(mx,sv[kt][r]);
      }
      mx=fmaxf(mx,__shfl_xor(mx,16)); mx=fmaxf(mx,__shfl_xor(mx,32));
      float sum=0.f;
      #pragma unroll
      for(int kt=0;kt<4;++kt){
        #pragma unroll
        for(int r=0;r<4;++r){ float e=__expf(sv[kt][r]-mx); sv[kt][r]=e; sum+=e; }
      }
      sum+=__shfl_xor(sum,16); sum+=__shfl_xor(sum,32);
      const float rs=1.f/sum;
      #pragma unroll
      for(int kt=0;kt<4;++kt){
        u16x4 pp;
        #pragma unroll
        for(int r=0;r<4;++r) pp[r]=f2b(sv[kt][r]*rs);
        *(u16x4*)(sm+p_off(q,(16*kt+4*lg)*2))=pp;   // P[q][ktok]
      }
      // ---- PV: A=VT rows=d, B=P cols=own q -> O[q][d] ----
      f32x4 ov[2]={(f32x4){0,0,0,0},(f32x4){0,0,0,0}};
      #pragma unroll
      for(int dt=0;dt<2;++dt){
        #pragma unroll
        for(int ks2=0;ks2<2;++ks2){
          const bf16x8 av=*(const bf16x8*)(sm+vt_off(16*dt+l16,ks2*64+lg*16));
          const bf16x8 bp=*(const bf16x8*)(sm+p_off(q,ks2*64+lg*16));
          ov[dt]=__builtin_amdgcn_mfma_f32_16x16x32_bf16(av,bp,ov[dt],0,0,0);
        }
      }
      #pragma unroll
      for(int dt=0;dt<2;++dt){
        u16x4 po;
        #pragma unroll
        for(int r=0;r<4;++r) po[r]=f2b(ov[dt][r]);
        *(u16x4*)(sm+o_off(q,(16*dt+4*lg)*2))=po;   // O[q][d]
      }
    }
    __syncthreads();   // O visible; Q/K/VT free to overwrite
    // ---- proj accumulate: A=Wproj rows=outch(wave's 3 tiles), B=O cols=tok ----
    {
      bf16x8 bo[4];
      #pragma unroll
      for(int tt=0;tt<4;++tt) bo[tt]=*(const bf16x8*)(sm+o_off(16*tt+l16,lg*16));
      #pragma unroll
      for(int mt=0;mt<3;++mt){
        const bf16x8 aw=*(const bf16x8*)(wprojT+(16*(3*w+mt)+l16)*192+h*32+lg*8);
        #pragma unroll
        for(int tt=0;tt<4;++tt)
          acc[mt][tt]=__builtin_amdgcn_mfma_f32_16x16x32_bf16(aw,bo[tt],acc[mt][tt],0,0,0);
      }
    }
    if(h<5){ c1(h+1); __syncthreads(); }
  }

  // ---- Phase D: t += proj + bias (registers only) ----
  #pragma unroll
  for(int mt=0;mt<3;++mt){
    const f32x4 bp=*(const f32x4*)(bproj+48*w+16*mt+4*lg);
    #pragma unroll
    for(int tt=0;tt<4;++tt){
      t[mt][tt]+=acc[mt][tt]+bp;
      acc[mt][tt]=(f32x4){0.f,0.f,0.f,0.f};
    }
  }

  // ---- LN2 -> h2 in SA ----
  layernorm(ln2g, ln2b);   // contains one barrier (red); first red write is safe: all waves past S(5)
  __syncthreads();         // h2 visible

  // ---- MLP: 4 chunks of 192 mch ----
  #pragma unroll 1
  for(int qc=0;qc<4;++qc){
    #pragma unroll 1
    for(int mt=0;mt<3;++mt){
      f32x4 g4[4];
      #pragma unroll
      for(int tt=0;tt<4;++tt) g4[tt]=(f32x4){0,0,0,0};
      #pragma unroll
      for(int ks=0;ks<6;++ks){
        const bf16x8 aw=*(const bf16x8*)(wmlp1T+(qc*192+16*(3*w+mt)+l16)*192+ks*32+lg*8);
        #pragma unroll
        for(int tt=0;tt<4;++tt){
          const bf16x8 bh2=*(const bf16x8*)(sm+sa_off(16*tt+l16,ks*64+lg*16));
          g4[tt]=__builtin_amdgcn_mfma_f32_16x16x32_bf16(aw,bh2,g4[tt],0,0,0);
        }
      }
      const f32x4 b1=*(const f32x4*)(bmlp1+qc*192+16*(3*w+mt)+4*lg);
      #pragma unroll
      for(int tt=0;tt<4;++tt){
        u16x4 pg;
        #pragma unroll
        for(int r=0;r<4;++r){
          const float xv=g4[tt][r]+b1[r];
          pg[r]=f2b(0.5f*xv*(1.f+erff(xv*0.70710678118654752f)));
        }
        *(u16x4*)(sm+g_off(16*tt+l16,(16*(3*w+mt)+4*lg)*2))=pg;  // G[tok][mch]
      }
    }
    __syncthreads();   // G visible
    #pragma unroll 1
    for(int ks=0;ks<6;++ks){
      bf16x8 bg[4];
      #pragma unroll
      for(int tt=0;tt<4;++tt) bg[tt]=*(const bf16x8*)(sm+g_off(16*tt+l16,ks*64+lg*16));
      #pragma unroll
      for(int mt=0;mt<3;++mt){
        const bf16x8 aw=*(const bf16x8*)(wmlp2T+(16*(3*w+mt)+l16)*768+qc*192+ks*32+lg*8);
        #pragma unroll
        for(int tt=0;tt<4;++tt)
          acc[mt][tt]=__builtin_amdgcn_mfma_f32_16x16x32_bf16(aw,bg[tt],acc[mt][tt],0,0,0);
      }
    }
    if(qc<3) __syncthreads();  // WAR before next G write
  }

  // ---- Final: out = t + mlp + bias ----
  if(DIRECT){
    #pragma unroll
    for(int mt=0;mt<3;++mt){
      const f32x4 b2=*(const f32x4*)(bmlp2+48*w+16*mt+4*lg);
      #pragma unroll
      for(int tt=0;tt<4;++tt){
        const int T=16*tt+l16, tp=(T>>3)*256+(T&7);
        #pragma unroll
        for(int r=0;r<4;++r)
          outp[imgoff+(size_t)(48*w+16*mt+4*lg+r)*65536+tp]=t[mt][tt][r]+acc[mt][tt][r]+b2[r];
      }
    }
  } else {
    float* wb = outp + (size_t)wid*12288;
    #pragma unroll
    for(int mt=0;mt<3;++mt){
      const f32x4 b2=*(const f32x4*)(bmlp2+48*w+16*mt+4*lg);
      #pragma unroll
      for(int tt=0;tt<4;++tt)
        *(f32x4*)(wb + (16*tt+l16)*192 + 48*w+16*mt+4*lg)=t[mt][tt]+acc[mt][tt]+b2;
    }
  }
}

extern "C" void kernel_launch(void* const* d_in, const int* in_sizes, int n_in,
                              void* d_out, int out_size, void* d_ws, size_t ws_size,
                              hipStream_t stream) {
  const float* x      = (const float*)d_in[0];
  const float* w_qkv  = (const float*)d_in[1];
  const float* b_qkv  = (const float*)d_in[2];
  const float* w_proj = (const float*)d_in[3];
  const float* b_proj = (const float*)d_in[4];
  const float* ln1g   = (const float*)d_in[5];
  const float* ln1b   = (const float*)d_in[6];
  const float* ln2g   = (const float*)d_in[7];
  const float* ln2b   = (const float*)d_in[8];
  const float* w_mlp1 = (const float*)d_in[9];
  const float* b_mlp1 = (const float*)d_in[10];
  const float* w_mlp2 = (const float*)d_in[11];
  const float* b_mlp2 = (const float*)d_in[12];
  unsigned short* wsu = (unsigned short*)d_ws;
  float* out = (float*)d_out;

  prep_weights<<<dim3(1728), dim3(256), 0, stream>>>(w_qkv, w_proj, w_mlp1, w_mlp2, wsu);

  const size_t need = (size_t)(1<<20) + 201326592ull;   // weights pad + xw
  if (ws_size >= need){
    float* xw = (float*)((char*)d_ws + (1<<20));
    relayout_in<<<dim3(1024), dim3(256), 0, stream>>>(x, xw);
    winblock<0><<<dim3(4096), dim3(256), 0, stream>>>(
        xw, xw, b_qkv, b_proj, ln1g, ln1b, ln2g, ln2b, b_mlp1, b_mlp2,
        wsu, wsu+110592, wsu+147456, wsu+294912);
    relayout_out<<<dim3(1024), dim3(256), 0, stream>>>(xw, out);
  } else {
    winblock<1><<<dim3(4096), dim3(256), 0, stream>>>(
        x, out, b_qkv, b_proj, ln1g, ln1b, ln2g, ln2b, b_mlp1, b_mlp2,
        wsu, wsu+110592, wsu+147456, wsu+294912);
  }
}

// Round 5
// 980.665 us; speedup vs baseline: 2.0211x; 1.2600x over previous
//
#include <hip/hip_runtime.h>
#include <hip/hip_bf16.h>
#include <math.h>

typedef float f32x4 __attribute__((ext_vector_type(4)));
typedef float f32x2 __attribute__((ext_vector_type(2)));
typedef __bf16 bf16x8 __attribute__((ext_vector_type(8)));
typedef unsigned short u16x4 __attribute__((ext_vector_type(4)));

// ---------------- LDS map (40960 B exactly -> 4 blocks/CU) ----------------
// SA  [64 tok][192 ch] bf16, stride 384, XOR((row&7)<<4)           : 24576
// RQ/RK/RO: tok-paired [32 rows][128 B] (2 toks/row)               : 3 x 4096
// RVT [32 d][64 tok] bf16, stride 128, XOR((row&7)<<4)             : 4096
// G (MLP, overlays RQ..RO+RVT) [64 tok][128 mch] bf16, stride 256  : 16384
// red (LN, overlays RQ)                                            : 2048
#define SA_B  0
#define RQ_B  24576
#define RK_B  28672
#define RVT_B 32768
#define RO_B  36864
#define RG_B  24576
#define SMEM  40960

__device__ __forceinline__ int sa_off(int row,int byte){ return SA_B + row*384 + (byte ^ ((row&7)<<4)); }
__device__ __forceinline__ int vt_off(int row,int byte){ return RVT_B+ row*128 + (byte ^ ((row&7)<<4)); }
__device__ __forceinline__ int g_off (int row,int byte){ return RG_B + row*256 + (byte ^ ((row&7)<<4)); }
// tok-paired: 2 toks per 128B row; conflict-free for both b128 reads and 8B writes
__device__ __forceinline__ int qp_off(int base,int tok,int byte){
  return base + (tok>>1)*128 + (tok&1)*64 + (byte ^ (((tok>>1)&7)<<4));
}
__device__ __forceinline__ unsigned short f2b(float x){ return __builtin_bit_cast(unsigned short, (__bf16)x); }

union U64 { unsigned long long u; u16x4 v; };
union U128 { unsigned long long q[2]; bf16x8 b; };

// Transpose + cast weights to bf16 [N][K]
__global__ void prep_weights(const float* __restrict__ wqkv, const float* __restrict__ wproj,
                             const float* __restrict__ wmlp1, const float* __restrict__ wmlp2,
                             unsigned short* __restrict__ ws){
  int idx = blockIdx.x*256 + threadIdx.x;
  if (idx < 110592){ int n=idx/192, k=idx%192; ws[idx] = f2b(wqkv[k*576+n]); }
  else if (idx < 147456){ int i=idx-110592; int n=i/192, k=i%192; ws[idx] = f2b(wproj[k*192+n]); }
  else if (idx < 294912){ int i=idx-147456; int n=i/192, k=i%192; ws[idx] = f2b(wmlp1[k*768+n]); }
  else if (idx < 442368){ int i=idx-294912; int n=i/768, k=i%768; ws[idx] = f2b(wmlp2[k*192+n]); }
}

// K1: x[B,C,H,W] -> xw[win][tok][192]
__global__ void relayout_in(const float* __restrict__ x, float* __restrict__ xw){
  const int w = threadIdx.x, bh = blockIdx.x, b = bh>>8, h = bh&255;
  const int win = b*1024 + (h>>3)*32 + (w>>3);
  const int tok = (h&7)*8 + (w&7);
  const size_t src = (size_t)b*192*65536 + (size_t)h*256 + w;
  float* dst = xw + (size_t)win*12288 + tok*192;
  #pragma unroll 1
  for(int c0=0;c0<192;c0+=32){
    float buf[32];
    #pragma unroll
    for(int j=0;j<32;++j) buf[j] = x[src + (size_t)(c0+j)*65536];
    #pragma unroll
    for(int j4=0;j4<8;++j4)
      *(f32x4*)(dst + c0 + j4*4) = (f32x4){buf[j4*4],buf[j4*4+1],buf[j4*4+2],buf[j4*4+3]};
  }
}

// K3: rw[win][tok][192] -> out[B,C,H,W]
__global__ void relayout_out(const float* __restrict__ rw, float* __restrict__ out){
  const int w = threadIdx.x, bh = blockIdx.x, b = bh>>8, h = bh&255;
  const int win = b*1024 + (h>>3)*32 + (w>>3);
  const int tok = (h&7)*8 + (w&7);
  const float* src = rw + (size_t)win*12288 + tok*192;
  const size_t dst = (size_t)b*192*65536 + (size_t)h*256 + w;
  #pragma unroll 1
  for(int c0=0;c0<192;c0+=32){
    f32x4 buf[8];
    #pragma unroll
    for(int j4=0;j4<8;++j4) buf[j4] = *(const f32x4*)(src + c0 + j4*4);
    #pragma unroll
    for(int j=0;j<32;++j) out[dst + (size_t)(c0+j)*65536] = buf[j>>2][j&3];
  }
}

// K2. Thread (w,lg,l16): owns toks {16tt+l16} x chs {48w+16mt+4lg+r}. 40KB LDS, <=128 VGPR.
template<int DIRECT>
__global__ void __launch_bounds__(256, 4) winblock(
    const float* xin, float* outp,
    const float* __restrict__ bqkv, const float* __restrict__ bproj,
    const float* __restrict__ ln1g, const float* __restrict__ ln1b,
    const float* __restrict__ ln2g, const float* __restrict__ ln2b,
    const float* __restrict__ bmlp1, const float* __restrict__ bmlp2,
    const unsigned short* __restrict__ wqkvT, const unsigned short* __restrict__ wprojT,
    const unsigned short* __restrict__ wmlp1T, const unsigned short* __restrict__ wmlp2T)
{
  __shared__ __align__(16) char sm[SMEM];
  const int tid=threadIdx.x, w=tid>>6, lg=(tid>>4)&3, l16=tid&15;
  const int wid=blockIdx.x;
  const int bb=wid>>10, wh=(wid>>5)&31, wwi=wid&31;
  const size_t imgoff=(size_t)bb*192*65536 + (size_t)(wh*8)*256 + (size_t)(wwi*8);
  f32x2* red = (f32x2*)(sm + RQ_B);

  // ---- residual t[mt][tt]: ch 48w+16mt+4lg+r, tok 16tt+l16 ----
  f32x4 t[3][4];
  if(DIRECT){
    #pragma unroll
    for(int mt=0;mt<3;++mt)
      #pragma unroll
      for(int tt=0;tt<4;++tt){
        const int T=16*tt+l16, tp=(T>>3)*256+(T&7);
        #pragma unroll
        for(int r=0;r<4;++r)
          t[mt][tt][r]=xin[imgoff+(size_t)(48*w+16*mt+4*lg+r)*65536+tp];
      }
  } else {
    const float* base = xin + (size_t)wid*12288;
    #pragma unroll
    for(int mt=0;mt<3;++mt)
      #pragma unroll
      for(int tt=0;tt<4;++tt)
        t[mt][tt]=*(const f32x4*)(base + (16*tt+l16)*192 + 48*w+16*mt+4*lg);
  }

  // ---- LayerNorm -> bf16 into SA (contains one internal barrier) ----
  auto layernorm = [&](const float* gg, const float* bbv){
    float s[4], s2[4];
    #pragma unroll
    for(int tt=0;tt<4;++tt){
      float a=0.f,b2=0.f;
      #pragma unroll
      for(int mt=0;mt<3;++mt){
        #pragma unroll
        for(int r=0;r<4;++r){ a+=t[mt][tt][r]; b2+=t[mt][tt][r]*t[mt][tt][r]; }
      }
      a+=__shfl_xor(a,16); a+=__shfl_xor(a,32);
      b2+=__shfl_xor(b2,16); b2+=__shfl_xor(b2,32);
      s[tt]=a; s2[tt]=b2;
    }
    if(lg==0) red[w*64 +  0+l16]=(f32x2){s[0],s2[0]};
    if(lg==1) red[w*64 + 16+l16]=(f32x2){s[1],s2[1]};
    if(lg==2) red[w*64 + 32+l16]=(f32x2){s[2],s2[2]};
    if(lg==3) red[w*64 + 48+l16]=(f32x2){s[3],s2[3]};
    __syncthreads();
    float mean[4], rstd[4];
    #pragma unroll
    for(int tt=0;tt<4;++tt){
      float S=0.f,S2=0.f;
      #pragma unroll
      for(int w2=0;w2<4;++w2){ f32x2 v=red[w2*64+16*tt+l16]; S+=v.x; S2+=v.y; }
      mean[tt]=S*(1.f/192.f);
      rstd[tt]=rsqrtf(S2*(1.f/192.f)-mean[tt]*mean[tt]+1e-5f);
    }
    #pragma unroll
    for(int mt=0;mt<3;++mt){
      const f32x4 g4=*(const f32x4*)(gg+48*w+16*mt+4*lg);
      const f32x4 b4=*(const f32x4*)(bbv+48*w+16*mt+4*lg);
      #pragma unroll
      for(int tt=0;tt<4;++tt){
        u16x4 pk;
        #pragma unroll
        for(int r=0;r<4;++r) pk[r]=f2b((t[mt][tt][r]-mean[tt])*rstd[tt]*g4[r]+b4[r]);
        *(u16x4*)(sm+sa_off(16*tt+l16,(48*w+16*mt+4*lg)*2))=pk;
      }
    }
  };

  layernorm(ln1g, ln1b);
  __syncthreads();   // h visible

  // ---- QKV producer: wave w -> ct=w>>1 (ch-half of head), tok-tiles {2(w&1),+1} ----
  const int ct=w>>1, tbase=2*(w&1);
  const float SOFT_SCALE = 0.17677669529663687f*1.4426950408889634f; // log2e/sqrt(32) into Q
  auto c1=[&](int hh){
    f32x4 qa[2],ka[2],va[2];
    #pragma unroll
    for(int i=0;i<2;++i){ qa[i]=(f32x4){0,0,0,0}; ka[i]=(f32x4){0,0,0,0}; va[i]=(f32x4){0,0,0,0}; }
    #pragma unroll
    for(int ks=0;ks<6;++ks){
      bf16x8 hfrag[2];
      #pragma unroll
      for(int i=0;i<2;++i) hfrag[i]=*(const bf16x8*)(sm+sa_off(16*(tbase+i)+l16, ks*64+lg*16));
      const bf16x8 awq=*(const bf16x8*)(wqkvT+(      hh*32+ct*16+l16)*192+ks*32+lg*8);
      const bf16x8 awk=*(const bf16x8*)(wqkvT+(192 + hh*32+ct*16+l16)*192+ks*32+lg*8);
      const bf16x8 bwv=*(const bf16x8*)(wqkvT+(384 + hh*32+ct*16+l16)*192+ks*32+lg*8);
      #pragma unroll
      for(int i=0;i<2;++i){
        qa[i]=__builtin_amdgcn_mfma_f32_16x16x32_bf16(awq,hfrag[i],qa[i],0,0,0);  // D[qch][tok]
        ka[i]=__builtin_amdgcn_mfma_f32_16x16x32_bf16(awk,hfrag[i],ka[i],0,0,0);
        va[i]=__builtin_amdgcn_mfma_f32_16x16x32_bf16(hfrag[i],bwv,va[i],0,0,0);  // D[tok][vch]
      }
    }
    const f32x4 bq4=*(const f32x4*)(bqkv+      hh*32+ct*16+4*lg);
    const f32x4 bk4=*(const f32x4*)(bqkv+192 + hh*32+ct*16+4*lg);
    const float bv =bqkv[384 + hh*32+ct*16+l16];
    #pragma unroll
    for(int i=0;i<2;++i){
      const int tok=16*(tbase+i)+l16;
      u16x4 pq,pk,pv;
      #pragma unroll
      for(int r=0;r<4;++r){
        pq[r]=f2b((qa[i][r]+bq4[r])*SOFT_SCALE);
        pk[r]=f2b(ka[i][r]+bk4[r]);
        pv[r]=f2b(va[i][r]+bv);
      }
      *(u16x4*)(sm+qp_off(RQ_B,tok,32*ct+8*lg))=pq;                  // Q[tok][qch]
      *(u16x4*)(sm+qp_off(RK_B,tok,32*ct+8*lg))=pk;                  // K[tok][qch]
      *(u16x4*)(sm+vt_off(ct*16+l16,(16*(tbase+i)+4*lg)*2))=pv;      // VT[vch][tok]
    }
  };

  c1(0);
  __syncthreads();

  #pragma unroll 1
  for(int h=0;h<6;++h){
    // ---- S^T = K.Q (A=K rows=ktok, B=Q col=own q) ; softmax in-register ----
    {
      const int q=16*w+l16;
      const bf16x8 bqf=*(const bf16x8*)(sm+qp_off(RQ_B,q,lg*16));
      f32x4 sv[4];
      #pragma unroll
      for(int kt=0;kt<4;++kt){
        const bf16x8 akf=*(const bf16x8*)(sm+qp_off(RK_B,16*kt+l16,lg*16));
        sv[kt]=__builtin_amdgcn_mfma_f32_16x16x32_bf16(akf,bqf,(f32x4){0,0,0,0},0,0,0);
      }
      float mx=-3.0e38f;
      #pragma unroll
      for(int kt=0;kt<4;++kt){
        #pragma unroll
        for(int r=0;r<4;++r) mx=fmaxf(mx,sv[kt][r]);
      }
      mx=fmaxf(mx,__shfl_xor(mx,16)); mx=fmaxf(mx,__shfl_xor(mx,32));
      float sum=0.f;
      #pragma unroll
      for(int kt=0;kt<4;++kt){
        #pragma unroll
        for(int r=0;r<4;++r){ float e=exp2f(sv[kt][r]-mx); sv[kt][r]=e; sum+=e; }
      }
      sum+=__shfl_xor(sum,16); sum+=__shfl_xor(sum,32);
      const float rs=1.f/sum;
      U64 pk0,pk1,pk2,pk3;
      #pragma unroll
      for(int r=0;r<4;++r){ pk0.v[r]=f2b(sv[0][r]*rs); pk1.v[r]=f2b(sv[1][r]*rs);
                            pk2.v[r]=f2b(sv[2][r]*rs); pk3.v[r]=f2b(sv[3][r]*rs); }
      // in-register P-fragment build: lane(lg,l16) needs ktok {8lg..8lg+7} (+32) for q=16w+l16
      const int srcA = ((lg&1)<<5) + l16, srcB = srcA + 16;
      unsigned long long rA0=__shfl(pk0.u,srcA), rB0=__shfl(pk0.u,srcB);
      unsigned long long rA1=__shfl(pk1.u,srcA), rB1=__shfl(pk1.u,srcB);
      unsigned long long rA2=__shfl(pk2.u,srcA), rB2=__shfl(pk2.u,srcB);
      unsigned long long rA3=__shfl(pk3.u,srcA), rB3=__shfl(pk3.u,srcB);
      U128 pf0, pf1;
      pf0.q[0]=(lg<2)?rA0:rA1;  pf0.q[1]=(lg<2)?rB0:rB1;   // ktok 0..31
      pf1.q[0]=(lg<2)?rA2:rA3;  pf1.q[1]=(lg<2)?rB2:rB3;   // ktok 32..63
      // ---- PV: A=VT (rows d), B=P (col=own q) -> D[d][q]; write O[q][d] ----
      f32x4 ov[2]={(f32x4){0,0,0,0},(f32x4){0,0,0,0}};
      #pragma unroll
      for(int dt=0;dt<2;++dt){
        const bf16x8 av0=*(const bf16x8*)(sm+vt_off(16*dt+l16,lg*16));
        const bf16x8 av1=*(const bf16x8*)(sm+vt_off(16*dt+l16,64+lg*16));
        ov[dt]=__builtin_amdgcn_mfma_f32_16x16x32_bf16(av0,pf0.b,ov[dt],0,0,0);
        ov[dt]=__builtin_amdgcn_mfma_f32_16x16x32_bf16(av1,pf1.b,ov[dt],0,0,0);
      }
      #pragma unroll
      for(int dt=0;dt<2;++dt){
        u16x4 po;
        #pragma unroll
        for(int r=0;r<4;++r) po[r]=f2b(ov[dt][r]);
        *(u16x4*)(sm+qp_off(RO_B,q,32*dt+8*lg))=po;   // own q row
      }
    }
    __syncthreads();   // O visible; Q/K/VT reads done
    // ---- proj accumulate directly into t: A=Wproj rows=own outch, B=O col=tok ----
    {
      bf16x8 bo[4];
      #pragma unroll
      for(int tt=0;tt<4;++tt) bo[tt]=*(const bf16x8*)(sm+qp_off(RO_B,16*tt+l16,lg*16));
      #pragma unroll
      for(int mt=0;mt<3;++mt){
        const bf16x8 aw=*(const bf16x8*)(wprojT+(16*(3*w+mt)+l16)*192+h*32+lg*8);
        #pragma unroll
        for(int tt=0;tt<4;++tt)
          t[mt][tt]=__builtin_amdgcn_mfma_f32_16x16x32_bf16(aw,bo[tt],t[mt][tt],0,0,0);
      }
    }
    if(h<5){ c1(h+1); __syncthreads(); }
  }

  // ---- proj bias once ----
  #pragma unroll
  for(int mt=0;mt<3;++mt){
    const f32x4 bp=*(const f32x4*)(bproj+48*w+16*mt+4*lg);
    #pragma unroll
    for(int tt=0;tt<4;++tt) t[mt][tt]+=bp;
  }

  // ---- LN2 (red overlays RQ; all Q reads finished) ----
  layernorm(ln2g, ln2b);
  __syncthreads();   // h2 visible; attn buffers dead -> G area free

  // ---- MLP: 6 chunks of 128 mch; MLP2 accumulates into t ----
  #pragma unroll 1
  for(int qc=0;qc<6;++qc){
    f32x4 g[2][4];
    #pragma unroll
    for(int m=0;m<2;++m)
      #pragma unroll
      for(int tt=0;tt<4;++tt) g[m][tt]=(f32x4){0,0,0,0};
    #pragma unroll
    for(int ks=0;ks<6;++ks){
      bf16x8 bh2[4];
      #pragma unroll
      for(int tt=0;tt<4;++tt) bh2[tt]=*(const bf16x8*)(sm+sa_off(16*tt+l16,ks*64+lg*16));
      #pragma unroll
      for(int m=0;m<2;++m){
        const bf16x8 aw=*(const bf16x8*)(wmlp1T+(qc*128+16*(2*w+m)+l16)*192+ks*32+lg*8);
        #pragma unroll
        for(int tt=0;tt<4;++tt)
          g[m][tt]=__builtin_amdgcn_mfma_f32_16x16x32_bf16(aw,bh2[tt],g[m][tt],0,0,0);
      }
    }
    #pragma unroll
    for(int m=0;m<2;++m){
      const f32x4 b1=*(const f32x4*)(bmlp1+qc*128+16*(2*w+m)+4*lg);
      #pragma unroll
      for(int tt=0;tt<4;++tt){
        u16x4 pg;
        #pragma unroll
        for(int r=0;r<4;++r){
          const float xv=g[m][tt][r]+b1[r];
          pg[r]=f2b(0.5f*xv*(1.f+erff(xv*0.70710678118654752f)));
        }
        *(u16x4*)(sm+g_off(16*tt+l16,(16*(2*w+m)+4*lg)*2))=pg;  // G[tok][mch]
      }
    }
    __syncthreads();   // G visible
    #pragma unroll
    for(int ks2=0;ks2<4;++ks2){
      bf16x8 bg[4];
      #pragma unroll
      for(int tt=0;tt<4;++tt) bg[tt]=*(const bf16x8*)(sm+g_off(16*tt+l16,ks2*64+lg*16));
      #pragma unroll
      for(int mt=0;mt<3;++mt){
        const bf16x8 aw2=*(const bf16x8*)(wmlp2T+(16*(3*w+mt)+l16)*768+qc*128+ks2*32+lg*8);
        #pragma unroll
        for(int tt=0;tt<4;++tt)
          t[mt][tt]=__builtin_amdgcn_mfma_f32_16x16x32_bf16(aw2,bg[tt],t[mt][tt],0,0,0);
      }
    }
    if(qc<5) __syncthreads();  // WAR before next G write
  }

  // ---- Final: out = t + bmlp2 ----
  if(DIRECT){
    #pragma unroll
    for(int mt=0;mt<3;++mt){
      const f32x4 b2=*(const f32x4*)(bmlp2+48*w+16*mt+4*lg);
      #pragma unroll
      for(int tt=0;tt<4;++tt){
        const int T=16*tt+l16, tp=(T>>3)*256+(T&7);
        #pragma unroll
        for(int r=0;r<4;++r)
          outp[imgoff+(size_t)(48*w+16*mt+4*lg+r)*65536+tp]=t[mt][tt][r]+b2[r];
      }
    }
  } else {
    float* wb = outp + (size_t)wid*12288;
    #pragma unroll
    for(int mt=0;mt<3;++mt){
      const f32x4 b2=*(const f32x4*)(bmlp2+48*w+16*mt+4*lg);
      #pragma unroll
      for(int tt=0;tt<4;++tt)
        *(f32x4*)(wb + (16*tt+l16)*192 + 48*w+16*mt+4*lg)=t[mt][tt]+b2;
    }
  }
}

extern "C" void kernel_launch(void* const* d_in, const int* in_sizes, int n_in,
                              void* d_out, int out_size, void* d_ws, size_t ws_size,
                              hipStream_t stream) {
  const float* x      = (const float*)d_in[0];
  const float* w_qkv  = (const float*)d_in[1];
  const float* b_qkv  = (const float*)d_in[2];
  const float* w_proj = (const float*)d_in[3];
  const float* b_proj = (const float*)d_in[4];
  const float* ln1g   = (const float*)d_in[5];
  const float* ln1b   = (const float*)d_in[6];
  const float* ln2g   = (const float*)d_in[7];
  const float* ln2b   = (const float*)d_in[8];
  const float* w_mlp1 = (const float*)d_in[9];
  const float* b_mlp1 = (const float*)d_in[10];
  const float* w_mlp2 = (const float*)d_in[11];
  const float* b_mlp2 = (const float*)d_in[12];
  unsigned short* wsu = (unsigned short*)d_ws;
  float* out = (float*)d_out;

  prep_weights<<<dim3(1728), dim3(256), 0, stream>>>(w_qkv, w_proj, w_mlp1, w_mlp2, wsu);

  const size_t need = (size_t)(1<<20) + 201326592ull;   // weights pad + xw
  if (ws_size >= need){
    float* xw = (float*)((char*)d_ws + (1<<20));
    relayout_in<<<dim3(1024), dim3(256), 0, stream>>>(x, xw);
    winblock<0><<<dim3(4096), dim3(256), 0, stream>>>(
        xw, xw, b_qkv, b_proj, ln1g, ln1b, ln2g, ln2b, b_mlp1, b_mlp2,
        wsu, wsu+110592, wsu+147456, wsu+294912);
    relayout_out<<<dim3(1024), dim3(256), 0, stream>>>(xw, out);
  } else {
    winblock<1><<<dim3(4096), dim3(256), 0, stream>>>(
        x, out, b_qkv, b_proj, ln1g, ln1b, ln2g, ln2b, b_mlp1, b_mlp2,
        wsu, wsu+110592, wsu+147456, wsu+294912);
  }
}